// Round 7
// baseline (1430.122 us; speedup 1.0000x reference)
//
#include <hip/hip_runtime.h>
#include <hip/hip_bf16.h>

// Problem constants (from reference setup_inputs)
#define BB    4
#define CC    256
#define HH    100
#define WW    152
#define NBOX  1000
#define PB    7          // OUTPUT_SIZE
#define SRR   2          // SAMPLING_RATIO
#define SCALE 0.25f      // SPATIAL_SCALE

#define S_HW        (HH * WW)                  // 15200
#define TILES_C     (CC / 32)                  // 8
#define TILES_PER_B ((S_HW / 32) * TILES_C)    // 3800
#define NTILES      (BB * TILES_PER_B)         // 15200
#define NITEMS      (2 * NBOX)                 // 2000
#define GRID        2048

struct Flags { int tclaim; int done[BB]; };    // zeroed per call (in-graph memset)

// ---------------------------------------------------------------------------
// Fused pipelined kernel.
// Phase A (work-stealing): global batch-major queue of 15200 transpose tiles
//   (f32 NCHW -> bf16 NHWC into ws). Each block steals tiles until its ROI's
//   batch is fully transposed (done[g]==3800). Deadlock-free under ANY
//   dispatch order: blocks sleep only when the queue is empty, at which point
//   every tile is claimed by an executing block (claims happen only during
//   execution), and transpose tiles never wait on anything.
// Phase B: R6's table-driven gather. 256 thr, lane owns 2 channels, wave w
//   does positions p = w+4j; per-(pos,sample) weights/offsets from LDS
//   broadcast; bf16 LDS staging drained as coalesced float4.
// LDS: union{ transpose tile 4224B | pw 3136 + po 3136 + obuf 12544 } = 18816B.
// ---------------------------------------------------------------------------
__global__ __launch_bounds__(256) void fused_kernel(
    const float* __restrict__ feat,
    const float* __restrict__ boxes,
    const int*   __restrict__ inds,
    ushort*      __restrict__ ft,
    Flags*       __restrict__ fl,
    float*       __restrict__ out)
{
    __shared__ __align__(16) char smem[18816];
    __shared__ int claim_slot;

    float  (*ttile)[33] = (float (*)[33])smem;       // phase A (4224 B)
    float4 *pw   = (float4*)smem;                    // phase B (3136 B)
    int4   *po   = (int4*)(smem + 3136);             // phase B (3136 B)
    ushort *obuf = (ushort*)(smem + 6272);           // phase B (12544 B)

    const int t = threadIdx.x;
    const int item      = blockIdx.x;                // GRID >= NITEMS
    const bool have_item = (item < NITEMS);
    const int n    = item >> 1;
    const int half = item & 1;
    const int g    = have_item ? inds[n] : 0;        // batch I need

    // ---------------- Phase A: steal transpose tiles ----------------
    bool qempty = false;                             // t==0 only
    for (;;) {
        if (t == 0) {
            int got;
            if (have_item &&
                __hip_atomic_load(&fl->done[g], __ATOMIC_RELAXED,
                                  __HIP_MEMORY_SCOPE_AGENT) >= TILES_PER_B) {
                got = -2;                            // my batch is ready
            } else if (!qempty) {
                const int c = __hip_atomic_fetch_add(&fl->tclaim, 1,
                                  __ATOMIC_RELAXED, __HIP_MEMORY_SCOPE_AGENT);
                if (c < NTILES) got = c;
                else { qempty = true; got = have_item ? -1 : -2; }
            } else {
                got = have_item ? -1 : -2;           // wait for in-flight tiles
            }
            claim_slot = got;
        }
        __syncthreads();
        const int got = claim_slot;
        if (got == -2) break;
        if (got == -1) {                             // queue empty, batch not done
            __builtin_amdgcn_s_sleep(16);
            __syncthreads();
            continue;
        }
        // transpose tile 'got' (batch-major order)
        const int b  = got / TILES_PER_B;
        const int r  = got % TILES_PER_B;
        const int ts = r / TILES_C;
        const int tc = r % TILES_C;
        const int s0 = ts * 32, c0 = tc * 32;
        const int tx = t & 31, ty4 = t >> 5;
        #pragma unroll
        for (int i = 0; i < 4; i++) {                // read: coalesced along s
            const int c = c0 + ty4 * 4 + i;
            const int s = s0 + tx;
            ttile[ty4 * 4 + i][tx] = feat[((size_t)b * CC + c) * S_HW + s];
        }
        __syncthreads();
        #pragma unroll
        for (int i = 0; i < 4; i++) {                // write: coalesced along c
            const int s = s0 + ty4 * 4 + i;
            const int c = c0 + tx;
            __hip_bfloat16 h = __float2bfloat16(ttile[tx][ty4 * 4 + i]);
            ft[((size_t)b * S_HW + s) * CC + c] = *(ushort*)&h;
        }
        __syncthreads();                             // vmcnt(0): stores at L2
        if (t == 0)                                  // release: wb + count
            __hip_atomic_fetch_add(&fl->done[b], 1, __ATOMIC_RELEASE,
                                   __HIP_MEMORY_SCOPE_AGENT);
    }

    if (!have_item) return;                          // helper blocks done

    __threadfence();                                 // acquire: fresh ft view
    __syncthreads();

    // ---------------- Phase B: gather (R6 body) ----------------
    if (t < PB * PB * SRR * SRR) {                   // 196 threads: tables
        const float x1 = boxes[n * 4 + 0] * SCALE;
        const float y1 = boxes[n * 4 + 1] * SCALE;
        const float x2 = boxes[n * 4 + 2] * SCALE;
        const float y2 = boxes[n * 4 + 3] * SCALE;
        const float bin_w = fmaxf(x2 - x1, 1.0f) * (1.0f / PB);
        const float bin_h = fmaxf(y2 - y1, 1.0f) * (1.0f / PB);
        const int p  = t >> 2;
        const int s  = t & 3;
        const int py = p / PB, px = p % PB;
        const int iy = s >> 1, ix = s & 1;
        const float yy = y1 + bin_h * (((float)(py * SRR + iy) + 0.5f) * (1.0f / SRR));
        const float xx = x1 + bin_w * (((float)(px * SRR + ix) + 0.5f) * (1.0f / SRR));
        const bool  v  = (yy > -1.0f) && (yy < (float)HH) &&
                         (xx > -1.0f) && (xx < (float)WW);
        const float m  = v ? (1.0f / (SRR * SRR)) : 0.0f;
        const float ycl = fminf(fmaxf(yy, 0.0f), (float)(HH - 1));
        const float xcl = fminf(fmaxf(xx, 0.0f), (float)(WW - 1));
        const int yl = (int)ycl, xl = (int)xcl;
        const int yh = min(yl + 1, HH - 1), xh = min(xl + 1, WW - 1);
        const float ly = ycl - (float)yl, lx = xcl - (float)xl;
        const float hy = 1.0f - ly,       hx = 1.0f - lx;
        pw[t] = make_float4(m * hy * hx, m * hy * lx, m * ly * hx, m * ly * lx);
        po[t] = make_int4((yl * WW + xl) * (CC * 2), (yl * WW + xh) * (CC * 2),
                          (yh * WW + xl) * (CC * 2), (yh * WW + xh) * (CC * 2));
    }
    __syncthreads();

    const int w  = t >> 6;                           // wave 0..3
    const int cl = 2 * (t & 63);                     // channel-local 0..126
    const char* fbase = (const char*)ft +
        ((size_t)g * (S_HW * CC) + half * 128 + cl) * 2;

#define LO(u) __uint_as_float((u) << 16)
#define HI(u) __uint_as_float((u) & 0xFFFF0000u)

#define POS_BODY(P)                                                           \
    {                                                                         \
        float a0 = 0.f, a1 = 0.f;                                             \
        _Pragma("unroll")                                                     \
        for (int s = 0; s < 4; s++) {                                         \
            const float4 wv = pw[(P) * 4 + s];                                \
            const int4   ov = po[(P) * 4 + s];                                \
            const uint u0 = *(const uint*)(fbase + ov.x);                     \
            const uint u1 = *(const uint*)(fbase + ov.y);                     \
            const uint u2 = *(const uint*)(fbase + ov.z);                     \
            const uint u3 = *(const uint*)(fbase + ov.w);                     \
            a0 += wv.x * LO(u0) + wv.y * LO(u1) + wv.z * LO(u2) + wv.w * LO(u3); \
            a1 += wv.x * HI(u0) + wv.y * HI(u1) + wv.z * HI(u2) + wv.w * HI(u3); \
        }                                                                     \
        __hip_bfloat16 h0 = __float2bfloat16(a0);                             \
        __hip_bfloat16 h1 = __float2bfloat16(a1);                             \
        obuf[(cl + 0) * (PB * PB) + (P)] = *(ushort*)&h0;                     \
        obuf[(cl + 1) * (PB * PB) + (P)] = *(ushort*)&h1;                     \
    }

    #pragma unroll
    for (int i = 0; i < 6; i++) {
        POS_BODY(w + 8 * i);
        POS_BODY(w + 8 * i + 4);
    }
    if (w == 0) POS_BODY(48);
#undef POS_BODY

    __syncthreads();
    // obuf flat (cl*49+p) == this half's output slab: coalesced drain
    const uint2* l2   = (const uint2*)obuf;
    float4*      out4 = (float4*)(out + ((size_t)n * CC + half * 128) * (PB * PB));
    for (int k = t; k < 128 * PB * PB / 4; k += 256) {
        const uint2 v = l2[k];
        out4[k] = make_float4(LO(v.x), HI(v.x), LO(v.y), HI(v.y));
    }
#undef LO
#undef HI
}

extern "C" void kernel_launch(void* const* d_in, const int* in_sizes, int n_in,
                              void* d_out, int out_size, void* d_ws, size_t ws_size,
                              hipStream_t stream)
{
    const float* feat  = (const float*)d_in[0];
    const float* boxes = (const float*)d_in[1];
    const int*   inds  = (const int*)d_in[2];
    float*       out   = (float*)d_out;

    ushort* ft = (ushort*)d_ws;                            // 31,129,600 B
    Flags*  fl = (Flags*)((char*)d_ws + (size_t)BB * S_HW * CC * 2);

    hipMemsetAsync(fl, 0, sizeof(Flags), stream);          // replay-safe reset
    fused_kernel<<<GRID, 256, 0, stream>>>(feat, boxes, inds, ft, fl, out);
}

// Round 8
// 87.300 us; speedup vs baseline: 16.3816x; 16.3816x over previous
//
#include <hip/hip_runtime.h>
#include <hip/hip_bf16.h>

// Problem constants (from reference setup_inputs)
#define BB    4
#define CC    256
#define HH    100
#define WW    152
#define NBOX  1000
#define PB    7          // OUTPUT_SIZE
#define SRR   2          // SAMPLING_RATIO
#define SCALE 0.25f      // SPATIAL_SCALE

// ---------------------------------------------------------------------------
// Transpose + downconvert: (B, C, H*W) f32 -> (B, H*W, C) bf16.
// ~93 MB -> ~16 us, ~93% of BW roofline. Proven, unchanged.
// ---------------------------------------------------------------------------
__global__ __launch_bounds__(256) void transpose_kernel(
    const float* __restrict__ in, ushort* __restrict__ out)
{
    __shared__ float tile[32][33];
    const int S = HH * WW;
    const int tilesS = S / 32;                 // 475
    const int tilesC = CC / 32;                // 8

    int bid = blockIdx.x;
    int b   = bid / (tilesS * tilesC);
    int r   = bid % (tilesS * tilesC);
    int ts  = r / tilesC;
    int tc  = r % tilesC;
    int s0  = ts * 32, c0 = tc * 32;

    int tx  = threadIdx.x & 31;
    int ty4 = threadIdx.x >> 5;

    #pragma unroll
    for (int i = 0; i < 4; i++) {
        int c = c0 + ty4 * 4 + i;
        int s = s0 + tx;
        tile[ty4 * 4 + i][tx] = in[((size_t)b * CC + c) * S + s];
    }
    __syncthreads();
    #pragma unroll
    for (int i = 0; i < 4; i++) {
        int s = s0 + ty4 * 4 + i;
        int c = c0 + tx;
        __hip_bfloat16 h = __float2bfloat16(tile[tx][ty4 * 4 + i]);
        out[((size_t)b * S + s) * CC + c] = *(ushort*)&h;
    }
}

// ---------------------------------------------------------------------------
// Main RoIAlign gather on transposed (B,H,W,C) bf16 features.
// grid = 2000 (ROI x channel-half), block = 256 thr = 4 waves, XCD-pair
// swizzle. Tables (weights + byte offsets) precomputed per block in LDS.
// KEY CHANGE vs R6: explicit 3-position LOAD/MATH grouping with named
// scalar results -> ~48 gather loads in flight per wave (was ~16; VGPR
// count showed the compiler kept only one position outstanding). This
// attacks L2/LLC latency, the hypothesized limiter after VMEM-count,
// VALU-count and occupancy changes all came back neutral.
// __launch_bounds__(256,8): pin 8 blocks/CU (32 waves), VGPR cap 64.
// ---------------------------------------------------------------------------
__global__ __launch_bounds__(256, 8) void roialign_kernel(
    const ushort* __restrict__ feat,
    const float*  __restrict__ boxes,
    const int*    __restrict__ inds,
    float*        __restrict__ out)
{
    __shared__ ushort obuf[128 * PB * PB];     // 12544 B bf16 out staging
    __shared__ float4 pw[PB * PB * SRR * SRR]; // 196 corner-weight quads
    __shared__ int4   po[PB * PB * SRR * SRR]; // 196 corner byte-offset quads

    // chunked XCD swizzle (2000 = 8 * 250, bijective; 250 even -> both
    // halves of an ROI land on the same XCD's L2)
    const int logical = (blockIdx.x & 7) * (2 * NBOX / 8) + (blockIdx.x >> 3);
    const int n    = logical >> 1;
    const int half = logical & 1;

    const int t  = threadIdx.x;
    const int w  = t >> 6;                     // wave 0..3
    const int cl = 2 * (t & 63);               // channel-local 0..126

    const int b = inds[n];

    if (t < PB * PB * SRR * SRR) {             // 196 threads: one (pos,sample)
        const float x1 = boxes[n * 4 + 0] * SCALE;
        const float y1 = boxes[n * 4 + 1] * SCALE;
        const float x2 = boxes[n * 4 + 2] * SCALE;
        const float y2 = boxes[n * 4 + 3] * SCALE;
        const float bin_w = fmaxf(x2 - x1, 1.0f) * (1.0f / PB);
        const float bin_h = fmaxf(y2 - y1, 1.0f) * (1.0f / PB);
        const int p  = t >> 2;
        const int s  = t & 3;
        const int py = p / PB, px = p % PB;
        const int iy = s >> 1, ix = s & 1;
        const float yy = y1 + bin_h * (((float)(py * SRR + iy) + 0.5f) * (1.0f / SRR));
        const float xx = x1 + bin_w * (((float)(px * SRR + ix) + 0.5f) * (1.0f / SRR));
        const bool  v  = (yy > -1.0f) && (yy < (float)HH) &&
                         (xx > -1.0f) && (xx < (float)WW);
        const float m  = v ? (1.0f / (SRR * SRR)) : 0.0f;   // inv folded in
        const float ycl = fminf(fmaxf(yy, 0.0f), (float)(HH - 1));
        const float xcl = fminf(fmaxf(xx, 0.0f), (float)(WW - 1));
        const int yl = (int)ycl, xl = (int)xcl;
        const int yh = min(yl + 1, HH - 1), xh = min(xl + 1, WW - 1);
        const float ly = ycl - (float)yl, lx = xcl - (float)xl;
        const float hy = 1.0f - ly,       hx = 1.0f - lx;
        pw[t] = make_float4(m * hy * hx, m * hy * lx, m * ly * hx, m * ly * lx);
        po[t] = make_int4((yl * WW + xl) * (CC * 2), (yl * WW + xh) * (CC * 2),
                          (yh * WW + xl) * (CC * 2), (yh * WW + xh) * (CC * 2));
    }
    __syncthreads();

    const char* fbase = (const char*)feat +
        ((size_t)b * (HH * WW * CC) + half * 128 + cl) * 2;

#define LO(u) __uint_as_float((u) << 16)
#define HI(u) __uint_as_float((u) & 0xFFFF0000u)
#define LD(off) (*(const uint*)(fbase + (off)))

    // Issue all 16 gathers of position P, keeping results in named regs.
#define LOADS(k, P)                                                           \
    uint u##k##_0, u##k##_1, u##k##_2, u##k##_3,                              \
         u##k##_4, u##k##_5, u##k##_6, u##k##_7,                              \
         u##k##_8, u##k##_9, u##k##_a, u##k##_b,                              \
         u##k##_c, u##k##_d, u##k##_e, u##k##_f;                              \
    {                                                                         \
        const int4 o0 = po[(P) * 4 + 0];                                      \
        const int4 o1 = po[(P) * 4 + 1];                                      \
        const int4 o2 = po[(P) * 4 + 2];                                      \
        const int4 o3 = po[(P) * 4 + 3];                                      \
        u##k##_0 = LD(o0.x); u##k##_1 = LD(o0.y);                             \
        u##k##_2 = LD(o0.z); u##k##_3 = LD(o0.w);                             \
        u##k##_4 = LD(o1.x); u##k##_5 = LD(o1.y);                             \
        u##k##_6 = LD(o1.z); u##k##_7 = LD(o1.w);                             \
        u##k##_8 = LD(o2.x); u##k##_9 = LD(o2.y);                             \
        u##k##_a = LD(o2.z); u##k##_b = LD(o2.w);                             \
        u##k##_c = LD(o3.x); u##k##_d = LD(o3.y);                             \
        u##k##_e = LD(o3.z); u##k##_f = LD(o3.w);                             \
    }

#define MATH(k, P)                                                            \
    {                                                                         \
        float a0 = 0.f, a1 = 0.f; float4 wv;                                  \
        wv = pw[(P) * 4 + 0];                                                 \
        a0 += wv.x * LO(u##k##_0) + wv.y * LO(u##k##_1)                       \
            + wv.z * LO(u##k##_2) + wv.w * LO(u##k##_3);                      \
        a1 += wv.x * HI(u##k##_0) + wv.y * HI(u##k##_1)                       \
            + wv.z * HI(u##k##_2) + wv.w * HI(u##k##_3);                      \
        wv = pw[(P) * 4 + 1];                                                 \
        a0 += wv.x * LO(u##k##_4) + wv.y * LO(u##k##_5)                       \
            + wv.z * LO(u##k##_6) + wv.w * LO(u##k##_7);                      \
        a1 += wv.x * HI(u##k##_4) + wv.y * HI(u##k##_5)                       \
            + wv.z * HI(u##k##_6) + wv.w * HI(u##k##_7);                      \
        wv = pw[(P) * 4 + 2];                                                 \
        a0 += wv.x * LO(u##k##_8) + wv.y * LO(u##k##_9)                       \
            + wv.z * LO(u##k##_a) + wv.w * LO(u##k##_b);                      \
        a1 += wv.x * HI(u##k##_8) + wv.y * HI(u##k##_9)                       \
            + wv.z * HI(u##k##_a) + wv.w * HI(u##k##_b);                      \
        wv = pw[(P) * 4 + 3];                                                 \
        a0 += wv.x * LO(u##k##_c) + wv.y * LO(u##k##_d)                       \
            + wv.z * LO(u##k##_e) + wv.w * LO(u##k##_f);                      \
        a1 += wv.x * HI(u##k##_c) + wv.y * HI(u##k##_d)                       \
            + wv.z * HI(u##k##_e) + wv.w * HI(u##k##_f);                      \
        __hip_bfloat16 h0 = __float2bfloat16(a0);                             \
        __hip_bfloat16 h1 = __float2bfloat16(a1);                             \
        obuf[(cl + 0) * (PB * PB) + (P)] = *(ushort*)&h0;                     \
        obuf[(cl + 1) * (PB * PB) + (P)] = *(ushort*)&h1;                     \
    }

    // wave w handles p = w + 4k, k = 0..11, in 4 groups of 3 with all
    // 48 loads issued before first use; wave 0 takes the p=48 tail.
    for (int j = 0; j < 12; j += 3) {
        const int p0 = w + 4 * j;
        const int p1 = p0 + 4;
        const int p2 = p0 + 8;
        LOADS(A, p0)
        LOADS(B, p1)
        LOADS(C, p2)
        MATH(A, p0)
        MATH(B, p1)
        MATH(C, p2)
    }
    if (w == 0) {
        LOADS(T, 48)
        MATH(T, 48)
    }
#undef LOADS
#undef MATH
#undef LD

    __syncthreads();
    // obuf flat (cl*49+p) == this half's output slab: coalesced drain
    const uint2* l2   = (const uint2*)obuf;
    float4*      out4 = (float4*)(out + ((size_t)n * CC + half * 128) * (PB * PB));
    for (int k = t; k < 128 * PB * PB / 4; k += 256) {
        const uint2 v = l2[k];
        out4[k] = make_float4(LO(v.x), HI(v.x), LO(v.y), HI(v.y));
    }
#undef LO
#undef HI
}

extern "C" void kernel_launch(void* const* d_in, const int* in_sizes, int n_in,
                              void* d_out, int out_size, void* d_ws, size_t ws_size,
                              hipStream_t stream)
{
    const float* feat  = (const float*)d_in[0];
    const float* boxes = (const float*)d_in[1];
    const int*   inds  = (const int*)d_in[2];
    float*       out   = (float*)d_out;

    ushort* ft = (ushort*)d_ws;                          // 31.13 MB bf16 feats
    const int tiles = BB * ((HH * WW) / 32) * (CC / 32); // 15200
    transpose_kernel<<<tiles, 256, 0, stream>>>(feat, ft);
    roialign_kernel<<<2 * NBOX, 256, 0, stream>>>(ft, boxes, inds, out);
}

// Round 9
// 57.551 us; speedup vs baseline: 24.8496x; 1.5169x over previous
//
#include <hip/hip_runtime.h>
#include <hip/hip_bf16.h>

// Problem constants (from reference setup_inputs)
#define BB    4
#define CC    256
#define HH    100
#define WW    152
#define NBOX  1000
#define PB    7          // OUTPUT_SIZE
#define SRR   2          // SAMPLING_RATIO
#define SCALE 0.25f      // SPATIAL_SCALE

// ---------------------------------------------------------------------------
// Transpose + downconvert: (B, C, H*W) f32 -> (B, H*W, C) bf16.
// ~93 MB -> ~16 us, ~93% of BW roofline. Proven, unchanged.
// ---------------------------------------------------------------------------
__global__ __launch_bounds__(256) void transpose_kernel(
    const float* __restrict__ in, ushort* __restrict__ out)
{
    __shared__ float tile[32][33];
    const int S = HH * WW;
    const int tilesS = S / 32;                 // 475
    const int tilesC = CC / 32;                // 8

    int bid = blockIdx.x;
    int b   = bid / (tilesS * tilesC);
    int r   = bid % (tilesS * tilesC);
    int ts  = r / tilesC;
    int tc  = r % tilesC;
    int s0  = ts * 32, c0 = tc * 32;

    int tx  = threadIdx.x & 31;
    int ty4 = threadIdx.x >> 5;

    #pragma unroll
    for (int i = 0; i < 4; i++) {
        int c = c0 + ty4 * 4 + i;
        int s = s0 + tx;
        tile[ty4 * 4 + i][tx] = in[((size_t)b * CC + c) * S + s];
    }
    __syncthreads();
    #pragma unroll
    for (int i = 0; i < 4; i++) {
        int s = s0 + ty4 * 4 + i;
        int c = c0 + tx;
        __hip_bfloat16 h = __float2bfloat16(tile[tx][ty4 * 4 + i]);
        out[((size_t)b * S + s) * CC + c] = *(ushort*)&h;
    }
}

// ---------------------------------------------------------------------------
// Main RoIAlign gather on transposed (B,H,W,C) bf16 features.
// grid = 2000 (ROI x channel-half), block = 256 thr = 4 waves, XCD-pair
// swizzle, per-block weight/offset tables in LDS (all proven-neutral but
// harmless). KEY: 3-position LOAD/MATH grouping -> 48 gather loads in
// flight per wave. R8 capped VGPR at 64 via __launch_bounds__(256,8) and
// the compiler SPILLED (WRITE_SIZE 139 MB, +40 us). This round:
// __launch_bounds__(256,4) -> 128 VGPR budget, 4 blocks/CU. Clean test of
// the latency-MLP hypothesis vs the fabric-ceiling hypothesis.
// ---------------------------------------------------------------------------
__global__ __launch_bounds__(256, 4) void roialign_kernel(
    const ushort* __restrict__ feat,
    const float*  __restrict__ boxes,
    const int*    __restrict__ inds,
    float*        __restrict__ out)
{
    __shared__ ushort obuf[128 * PB * PB];     // 12544 B bf16 out staging
    __shared__ float4 pw[PB * PB * SRR * SRR]; // 196 corner-weight quads
    __shared__ int4   po[PB * PB * SRR * SRR]; // 196 corner byte-offset quads

    // chunked XCD swizzle (2000 = 8 * 250, bijective; 250 even -> both
    // halves of an ROI land on the same XCD's L2)
    const int logical = (blockIdx.x & 7) * (2 * NBOX / 8) + (blockIdx.x >> 3);
    const int n    = logical >> 1;
    const int half = logical & 1;

    const int t  = threadIdx.x;
    const int w  = t >> 6;                     // wave 0..3
    const int cl = 2 * (t & 63);               // channel-local 0..126

    const int b = inds[n];

    if (t < PB * PB * SRR * SRR) {             // 196 threads: one (pos,sample)
        const float x1 = boxes[n * 4 + 0] * SCALE;
        const float y1 = boxes[n * 4 + 1] * SCALE;
        const float x2 = boxes[n * 4 + 2] * SCALE;
        const float y2 = boxes[n * 4 + 3] * SCALE;
        const float bin_w = fmaxf(x2 - x1, 1.0f) * (1.0f / PB);
        const float bin_h = fmaxf(y2 - y1, 1.0f) * (1.0f / PB);
        const int p  = t >> 2;
        const int s  = t & 3;
        const int py = p / PB, px = p % PB;
        const int iy = s >> 1, ix = s & 1;
        const float yy = y1 + bin_h * (((float)(py * SRR + iy) + 0.5f) * (1.0f / SRR));
        const float xx = x1 + bin_w * (((float)(px * SRR + ix) + 0.5f) * (1.0f / SRR));
        const bool  v  = (yy > -1.0f) && (yy < (float)HH) &&
                         (xx > -1.0f) && (xx < (float)WW);
        const float m  = v ? (1.0f / (SRR * SRR)) : 0.0f;   // inv folded in
        const float ycl = fminf(fmaxf(yy, 0.0f), (float)(HH - 1));
        const float xcl = fminf(fmaxf(xx, 0.0f), (float)(WW - 1));
        const int yl = (int)ycl, xl = (int)xcl;
        const int yh = min(yl + 1, HH - 1), xh = min(xl + 1, WW - 1);
        const float ly = ycl - (float)yl, lx = xcl - (float)xl;
        const float hy = 1.0f - ly,       hx = 1.0f - lx;
        pw[t] = make_float4(m * hy * hx, m * hy * lx, m * ly * hx, m * ly * lx);
        po[t] = make_int4((yl * WW + xl) * (CC * 2), (yl * WW + xh) * (CC * 2),
                          (yh * WW + xl) * (CC * 2), (yh * WW + xh) * (CC * 2));
    }
    __syncthreads();

    const char* fbase = (const char*)feat +
        ((size_t)b * (HH * WW * CC) + half * 128 + cl) * 2;

#define LO(u) __uint_as_float((u) << 16)
#define HI(u) __uint_as_float((u) & 0xFFFF0000u)
#define LD(off) (*(const uint*)(fbase + (off)))

    // Issue all 16 gathers of position P, keeping results in named regs.
#define LOADS(k, P)                                                           \
    uint u##k##_0, u##k##_1, u##k##_2, u##k##_3,                              \
         u##k##_4, u##k##_5, u##k##_6, u##k##_7,                              \
         u##k##_8, u##k##_9, u##k##_a, u##k##_b,                              \
         u##k##_c, u##k##_d, u##k##_e, u##k##_f;                              \
    {                                                                         \
        const int4 o0 = po[(P) * 4 + 0];                                      \
        const int4 o1 = po[(P) * 4 + 1];                                      \
        const int4 o2 = po[(P) * 4 + 2];                                      \
        const int4 o3 = po[(P) * 4 + 3];                                      \
        u##k##_0 = LD(o0.x); u##k##_1 = LD(o0.y);                             \
        u##k##_2 = LD(o0.z); u##k##_3 = LD(o0.w);                             \
        u##k##_4 = LD(o1.x); u##k##_5 = LD(o1.y);                             \
        u##k##_6 = LD(o1.z); u##k##_7 = LD(o1.w);                             \
        u##k##_8 = LD(o2.x); u##k##_9 = LD(o2.y);                             \
        u##k##_a = LD(o2.z); u##k##_b = LD(o2.w);                             \
        u##k##_c = LD(o3.x); u##k##_d = LD(o3.y);                             \
        u##k##_e = LD(o3.z); u##k##_f = LD(o3.w);                             \
    }

#define MATH(k, P)                                                            \
    {                                                                         \
        float a0 = 0.f, a1 = 0.f; float4 wv;                                  \
        wv = pw[(P) * 4 + 0];                                                 \
        a0 += wv.x * LO(u##k##_0) + wv.y * LO(u##k##_1)                       \
            + wv.z * LO(u##k##_2) + wv.w * LO(u##k##_3);                      \
        a1 += wv.x * HI(u##k##_0) + wv.y * HI(u##k##_1)                       \
            + wv.z * HI(u##k##_2) + wv.w * HI(u##k##_3);                      \
        wv = pw[(P) * 4 + 1];                                                 \
        a0 += wv.x * LO(u##k##_4) + wv.y * LO(u##k##_5)                       \
            + wv.z * LO(u##k##_6) + wv.w * LO(u##k##_7);                      \
        a1 += wv.x * HI(u##k##_4) + wv.y * HI(u##k##_5)                       \
            + wv.z * HI(u##k##_6) + wv.w * HI(u##k##_7);                      \
        wv = pw[(P) * 4 + 2];                                                 \
        a0 += wv.x * LO(u##k##_8) + wv.y * LO(u##k##_9)                       \
            + wv.z * LO(u##k##_a) + wv.w * LO(u##k##_b);                      \
        a1 += wv.x * HI(u##k##_8) + wv.y * HI(u##k##_9)                       \
            + wv.z * HI(u##k##_a) + wv.w * HI(u##k##_b);                      \
        wv = pw[(P) * 4 + 3];                                                 \
        a0 += wv.x * LO(u##k##_c) + wv.y * LO(u##k##_d)                       \
            + wv.z * LO(u##k##_e) + wv.w * LO(u##k##_f);                      \
        a1 += wv.x * HI(u##k##_c) + wv.y * HI(u##k##_d)                       \
            + wv.z * HI(u##k##_e) + wv.w * HI(u##k##_f);                      \
        __hip_bfloat16 h0 = __float2bfloat16(a0);                             \
        __hip_bfloat16 h1 = __float2bfloat16(a1);                             \
        obuf[(cl + 0) * (PB * PB) + (P)] = *(ushort*)&h0;                     \
        obuf[(cl + 1) * (PB * PB) + (P)] = *(ushort*)&h1;                     \
    }

    // wave w handles p = w + 4k, k = 0..11, in 4 groups of 3 with all
    // 48 loads issued before first use; wave 0 takes the p=48 tail.
    for (int j = 0; j < 12; j += 3) {
        const int p0 = w + 4 * j;
        const int p1 = p0 + 4;
        const int p2 = p0 + 8;
        LOADS(A, p0)
        LOADS(B, p1)
        LOADS(C, p2)
        MATH(A, p0)
        MATH(B, p1)
        MATH(C, p2)
    }
    if (w == 0) {
        LOADS(T, 48)
        MATH(T, 48)
    }
#undef LOADS
#undef MATH
#undef LD

    __syncthreads();
    // obuf flat (cl*49+p) == this half's output slab: coalesced drain
    const uint2* l2   = (const uint2*)obuf;
    float4*      out4 = (float4*)(out + ((size_t)n * CC + half * 128) * (PB * PB));
    for (int k = t; k < 128 * PB * PB / 4; k += 256) {
        const uint2 v = l2[k];
        out4[k] = make_float4(LO(v.x), HI(v.x), LO(v.y), HI(v.y));
    }
#undef LO
#undef HI
}

extern "C" void kernel_launch(void* const* d_in, const int* in_sizes, int n_in,
                              void* d_out, int out_size, void* d_ws, size_t ws_size,
                              hipStream_t stream)
{
    const float* feat  = (const float*)d_in[0];
    const float* boxes = (const float*)d_in[1];
    const int*   inds  = (const int*)d_in[2];
    float*       out   = (float*)d_out;

    ushort* ft = (ushort*)d_ws;                          // 31.13 MB bf16 feats
    const int tiles = BB * ((HH * WW) / 32) * (CC / 32); // 15200
    transpose_kernel<<<tiles, 256, 0, stream>>>(feat, ft);
    roialign_kernel<<<2 * NBOX, 256, 0, stream>>>(ft, boxes, inds, out);
}

// Round 10
// 51.775 us; speedup vs baseline: 27.6220x; 1.1116x over previous
//
#include <hip/hip_runtime.h>
#include <hip/hip_bf16.h>

// Problem constants (from reference setup_inputs)
#define BB    4
#define CC    256
#define HH    100
#define WW    152
#define NBOX  1000
#define PB    7          // OUTPUT_SIZE
#define SRR   2          // SAMPLING_RATIO
#define SCALE 0.25f      // SPATIAL_SCALE

// ---------------------------------------------------------------------------
// Transpose + downconvert: (B, C, H*W) f32 -> (B, H*W, C) bf16.
// ~93 MB -> ~16 us, ~93% of BW roofline. Proven, unchanged.
// ---------------------------------------------------------------------------
__global__ __launch_bounds__(256) void transpose_kernel(
    const float* __restrict__ in, ushort* __restrict__ out)
{
    __shared__ float tile[32][33];
    const int S = HH * WW;
    const int tilesS = S / 32;                 // 475
    const int tilesC = CC / 32;                // 8

    int bid = blockIdx.x;
    int b   = bid / (tilesS * tilesC);
    int r   = bid % (tilesS * tilesC);
    int ts  = r / tilesC;
    int tc  = r % tilesC;
    int s0  = ts * 32, c0 = tc * 32;

    int tx  = threadIdx.x & 31;
    int ty4 = threadIdx.x >> 5;

    #pragma unroll
    for (int i = 0; i < 4; i++) {
        int c = c0 + ty4 * 4 + i;
        int s = s0 + tx;
        tile[ty4 * 4 + i][tx] = in[((size_t)b * CC + c) * S + s];
    }
    __syncthreads();
    #pragma unroll
    for (int i = 0; i < 4; i++) {
        int s = s0 + ty4 * 4 + i;
        int c = c0 + tx;
        __hip_bfloat16 h = __float2bfloat16(tile[tx][ty4 * 4 + i]);
        out[((size_t)b * S + s) * CC + c] = *(ushort*)&h;
    }
}

// ---------------------------------------------------------------------------
// Main RoIAlign gather on transposed (B,H,W,C) bf16 features.
// R6 structure (grid 2000, 256 thr, tables, XCD-pair swizzle, bf16 obuf).
// KEY CHANGE vs R9: an asm memory-clobber fence between the 3-position
// LOADS group and the MATH group. R9 proved the compiler's pressure
// heuristic re-sinks loads to uses (VGPR stayed 52) even with a 128-reg
// budget. Loads cannot move across a "memory" clobber, so all 48 gathers
// must be issued (and held in regs) before the first use -> true 48-deep
// MLP per wave. No launch-bounds pin: R8 showed pins cause spills; let
// VGPR float (~90-110 expected, occupancy ~5 blocks/CU).
// ---------------------------------------------------------------------------
__global__ __launch_bounds__(256) void roialign_kernel(
    const ushort* __restrict__ feat,
    const float*  __restrict__ boxes,
    const int*    __restrict__ inds,
    float*        __restrict__ out)
{
    __shared__ ushort obuf[128 * PB * PB];     // 12544 B bf16 out staging
    __shared__ float4 pw[PB * PB * SRR * SRR]; // 196 corner-weight quads
    __shared__ int4   po[PB * PB * SRR * SRR]; // 196 corner byte-offset quads

    // chunked XCD swizzle (2000 = 8 * 250, bijective; 250 even -> both
    // halves of an ROI land on the same XCD's L2)
    const int logical = (blockIdx.x & 7) * (2 * NBOX / 8) + (blockIdx.x >> 3);
    const int n    = logical >> 1;
    const int half = logical & 1;

    const int t  = threadIdx.x;
    const int w  = t >> 6;                     // wave 0..3
    const int cl = 2 * (t & 63);               // channel-local 0..126

    const int b = inds[n];

    if (t < PB * PB * SRR * SRR) {             // 196 threads: one (pos,sample)
        const float x1 = boxes[n * 4 + 0] * SCALE;
        const float y1 = boxes[n * 4 + 1] * SCALE;
        const float x2 = boxes[n * 4 + 2] * SCALE;
        const float y2 = boxes[n * 4 + 3] * SCALE;
        const float bin_w = fmaxf(x2 - x1, 1.0f) * (1.0f / PB);
        const float bin_h = fmaxf(y2 - y1, 1.0f) * (1.0f / PB);
        const int p  = t >> 2;
        const int s  = t & 3;
        const int py = p / PB, px = p % PB;
        const int iy = s >> 1, ix = s & 1;
        const float yy = y1 + bin_h * (((float)(py * SRR + iy) + 0.5f) * (1.0f / SRR));
        const float xx = x1 + bin_w * (((float)(px * SRR + ix) + 0.5f) * (1.0f / SRR));
        const bool  v  = (yy > -1.0f) && (yy < (float)HH) &&
                         (xx > -1.0f) && (xx < (float)WW);
        const float m  = v ? (1.0f / (SRR * SRR)) : 0.0f;   // inv folded in
        const float ycl = fminf(fmaxf(yy, 0.0f), (float)(HH - 1));
        const float xcl = fminf(fmaxf(xx, 0.0f), (float)(WW - 1));
        const int yl = (int)ycl, xl = (int)xcl;
        const int yh = min(yl + 1, HH - 1), xh = min(xl + 1, WW - 1);
        const float ly = ycl - (float)yl, lx = xcl - (float)xl;
        const float hy = 1.0f - ly,       hx = 1.0f - lx;
        pw[t] = make_float4(m * hy * hx, m * hy * lx, m * ly * hx, m * ly * lx);
        po[t] = make_int4((yl * WW + xl) * (CC * 2), (yl * WW + xh) * (CC * 2),
                          (yh * WW + xl) * (CC * 2), (yh * WW + xh) * (CC * 2));
    }
    __syncthreads();

    const char* fbase = (const char*)feat +
        ((size_t)b * (HH * WW * CC) + half * 128 + cl) * 2;

#define LO(u) __uint_as_float((u) << 16)
#define HI(u) __uint_as_float((u) & 0xFFFF0000u)
#define LD(off) (*(const uint*)(fbase + (off)))

    // Issue all 16 gathers of position P, keeping results in named regs.
#define LOADS(k, P)                                                           \
    uint u##k##_0, u##k##_1, u##k##_2, u##k##_3,                              \
         u##k##_4, u##k##_5, u##k##_6, u##k##_7,                              \
         u##k##_8, u##k##_9, u##k##_a, u##k##_b,                              \
         u##k##_c, u##k##_d, u##k##_e, u##k##_f;                              \
    {                                                                         \
        const int4 o0 = po[(P) * 4 + 0];                                      \
        const int4 o1 = po[(P) * 4 + 1];                                      \
        const int4 o2 = po[(P) * 4 + 2];                                      \
        const int4 o3 = po[(P) * 4 + 3];                                      \
        u##k##_0 = LD(o0.x); u##k##_1 = LD(o0.y);                             \
        u##k##_2 = LD(o0.z); u##k##_3 = LD(o0.w);                             \
        u##k##_4 = LD(o1.x); u##k##_5 = LD(o1.y);                             \
        u##k##_6 = LD(o1.z); u##k##_7 = LD(o1.w);                             \
        u##k##_8 = LD(o2.x); u##k##_9 = LD(o2.y);                             \
        u##k##_a = LD(o2.z); u##k##_b = LD(o2.w);                             \
        u##k##_c = LD(o3.x); u##k##_d = LD(o3.y);                             \
        u##k##_e = LD(o3.z); u##k##_f = LD(o3.w);                             \
    }

#define MATH(k, P)                                                            \
    {                                                                         \
        float a0 = 0.f, a1 = 0.f; float4 wv;                                  \
        wv = pw[(P) * 4 + 0];                                                 \
        a0 += wv.x * LO(u##k##_0) + wv.y * LO(u##k##_1)                       \
            + wv.z * LO(u##k##_2) + wv.w * LO(u##k##_3);                      \
        a1 += wv.x * HI(u##k##_0) + wv.y * HI(u##k##_1)                       \
            + wv.z * HI(u##k##_2) + wv.w * HI(u##k##_3);                      \
        wv = pw[(P) * 4 + 1];                                                 \
        a0 += wv.x * LO(u##k##_4) + wv.y * LO(u##k##_5)                       \
            + wv.z * LO(u##k##_6) + wv.w * LO(u##k##_7);                      \
        a1 += wv.x * HI(u##k##_4) + wv.y * HI(u##k##_5)                       \
            + wv.z * HI(u##k##_6) + wv.w * HI(u##k##_7);                      \
        wv = pw[(P) * 4 + 2];                                                 \
        a0 += wv.x * LO(u##k##_8) + wv.y * LO(u##k##_9)                       \
            + wv.z * LO(u##k##_a) + wv.w * LO(u##k##_b);                      \
        a1 += wv.x * HI(u##k##_8) + wv.y * HI(u##k##_9)                       \
            + wv.z * HI(u##k##_a) + wv.w * HI(u##k##_b);                      \
        wv = pw[(P) * 4 + 3];                                                 \
        a0 += wv.x * LO(u##k##_c) + wv.y * LO(u##k##_d)                       \
            + wv.z * LO(u##k##_e) + wv.w * LO(u##k##_f);                      \
        a1 += wv.x * HI(u##k##_c) + wv.y * HI(u##k##_d)                       \
            + wv.z * HI(u##k##_e) + wv.w * HI(u##k##_f);                      \
        __hip_bfloat16 h0 = __float2bfloat16(a0);                             \
        __hip_bfloat16 h1 = __float2bfloat16(a1);                             \
        obuf[(cl + 0) * (PB * PB) + (P)] = *(ushort*)&h0;                     \
        obuf[(cl + 1) * (PB * PB) + (P)] = *(ushort*)&h1;                     \
    }

    // wave w handles p = w + 4k, k = 0..11, in 4 groups of 3. The asm
    // memory clobber pins all 48 loads ABOVE the first use: the compiler
    // cannot sink a load across it, so the wave has 48 gathers in flight.
    for (int j = 0; j < 12; j += 3) {
        const int p0 = w + 4 * j;
        const int p1 = p0 + 4;
        const int p2 = p0 + 8;
        LOADS(A, p0)
        LOADS(B, p1)
        LOADS(C, p2)
        asm volatile("" ::: "memory");   // fence: no load sinking
        MATH(A, p0)
        MATH(B, p1)
        MATH(C, p2)
    }
    if (w == 0) {
        LOADS(T, 48)
        MATH(T, 48)
    }
#undef LOADS
#undef MATH
#undef LD

    __syncthreads();
    // obuf flat (cl*49+p) == this half's output slab: coalesced drain
    const uint2* l2   = (const uint2*)obuf;
    float4*      out4 = (float4*)(out + ((size_t)n * CC + half * 128) * (PB * PB));
    for (int k = t; k < 128 * PB * PB / 4; k += 256) {
        const uint2 v = l2[k];
        out4[k] = make_float4(LO(v.x), HI(v.x), LO(v.y), HI(v.y));
    }
#undef LO
#undef HI
}

extern "C" void kernel_launch(void* const* d_in, const int* in_sizes, int n_in,
                              void* d_out, int out_size, void* d_ws, size_t ws_size,
                              hipStream_t stream)
{
    const float* feat  = (const float*)d_in[0];
    const float* boxes = (const float*)d_in[1];
    const int*   inds  = (const int*)d_in[2];
    float*       out   = (float*)d_out;

    ushort* ft = (ushort*)d_ws;                          // 31.13 MB bf16 feats
    const int tiles = BB * ((HH * WW) / 32) * (CC / 32); // 15200
    transpose_kernel<<<tiles, 256, 0, stream>>>(feat, ft);
    roialign_kernel<<<2 * NBOX, 256, 0, stream>>>(ft, boxes, inds, out);
}